// Round 12
// baseline (196.188 us; speedup 1.0000x reference)
//
#include <hip/hip_runtime.h>
#include <math.h>

// S4 conv: y = irfft(rfft(u,8192)*rfft(K,8192))[:4096] + D*u ; K shared by all rows.
// Round 12: r11 structure (k_at + fused k_Gab prep + r6 k_conv) with twiddle
// TABLES replacing per-thread sincos+power-chains in k_conv (~13% of its VALU
// inst computed identically in all 4096 blocks). T1[k][tid] 28KB global->regs
// (conjugated reuse in inverse), T2/T3 in LDS (+3.9KB -> 36.8KB, still 4
// blocks/CU). Exchanges/swizzles/barriers/dft8 byte-identical to r6 k_conv.

#define SEQ_L 4096
#define M4    4096
#define NFFT  8192
#define NST   64
#define NROWS 8192
#define TWO_PI 6.28318530717958647692f

typedef float2 cf;

__device__ __forceinline__ cf cmul(cf a, cf b){ return make_float2(a.x*b.x - a.y*b.y, a.x*b.y + a.y*b.x); }
// a * conj(b)
__device__ __forceinline__ cf cmulc(cf a, cf b){ return make_float2(a.x*b.x + a.y*b.y, a.y*b.x - a.x*b.y); }
__device__ __forceinline__ cf cadd(cf a, cf b){ return make_float2(a.x+b.x, a.y+b.y); }
__device__ __forceinline__ cf csub(cf a, cf b){ return make_float2(a.x-b.x, a.y-b.y); }
__device__ __forceinline__ double2 dcmul(double2 a, double2 b) {
  return make_double2(a.x*b.x - a.y*b.y, a.x*b.y + a.y*b.x);
}

// k_conv / phase-1 swizzles (4096-cf space); involutions
__device__ __forceinline__ int s2f(int i){ return i ^ (((i >> 6) & 1) << 3); }
__device__ __forceinline__ int s3f(int i){ return i ^ ((i >> 6) & 7) ^ (((i >> 6) & 1) << 3); }
__device__ __forceinline__ int smf(int i){ return i ^ ((i >> 6) & 7); }
// phase-2 swizzle (8192-cf space)
__device__ __forceinline__ int sw(int p){ return p ^ ((p >> 4) & 15); }

template<int S>
__device__ __forceinline__ void r4(cf& a0, cf& a1, cf& a2, cf& a3){
  cf t0 = cadd(a0,a2), t1 = csub(a0,a2);
  cf t2 = cadd(a1,a3), t3 = csub(a1,a3);
  cf w = (S < 0) ? make_float2(t3.y, -t3.x) : make_float2(-t3.y, t3.x);
  a0 = cadd(t0,t2); a2 = csub(t0,t2);
  a1 = cadd(t1,w);  a3 = csub(t1,w);
}

template<int S, bool ZHI, bool LO4=false>
__device__ __forceinline__ void dft8(cf x[8]){
  const float C = 0.70710678118654752f;
  cf e0,e1,e2,e3,o0,o1,o2,o3;
  if (ZHI) {
    cf w  = (S<0)? make_float2(x[2].y,-x[2].x) : make_float2(-x[2].y,x[2].x);
    e0 = cadd(x[0],x[2]); e2 = csub(x[0],x[2]);
    e1 = cadd(x[0],w);    e3 = csub(x[0],w);
    cf w2 = (S<0)? make_float2(x[3].y,-x[3].x) : make_float2(-x[3].y,x[3].x);
    o0 = cadd(x[1],x[3]); o2 = csub(x[1],x[3]);
    o1 = cadd(x[1],w2);   o3 = csub(x[1],w2);
  } else {
    cf a0=x[0],a1=x[2],a2=x[4],a3=x[6];
    r4<S>(a0,a1,a2,a3);  e0=a0;e1=a1;e2=a2;e3=a3;
    cf b0=x[1],b1=x[3],b2=x[5],b3=x[7];
    r4<S>(b0,b1,b2,b3);  o0=b0;o1=b1;o2=b2;o3=b3;
  }
  x[0] = cadd(e0,o0); if (!LO4) x[4] = csub(e0,o0);
  cf t1 = (S<0)? make_float2(C*(o1.x+o1.y), C*(o1.y-o1.x))
               : make_float2(C*(o1.x-o1.y), C*(o1.x+o1.y));
  x[1] = cadd(e1,t1); if (!LO4) x[5] = csub(e1,t1);
  cf t2 = (S<0)? make_float2(o2.y,-o2.x) : make_float2(-o2.y,o2.x);
  x[2] = cadd(e2,t2); if (!LO4) x[6] = csub(e2,t2);
  cf t3 = (S<0)? make_float2(C*(o3.y-o3.x), -C*(o3.x+o3.y))
               : make_float2(-C*(o3.x+o3.y), C*(o3.x-o3.y));
  x[3] = cadd(e3,t3); if (!LO4) x[7] = csub(e3,t3);
}

// sincos-based chain (used only in prep's k_Gab, runs once)
__device__ __forceinline__ void chain8(cf x[8], float th){
  float sn, cs; __sincosf(th, &sn, &cs);
  cf w1 = make_float2(cs, sn);
  cf w2 = cmul(w1, w1);
  cf w3 = cmul(w2, w1);
  x[1] = cmul(x[1], w1); x[2] = cmul(x[2], w2); x[3] = cmul(x[3], w3);
  cf w4 = cmul(w2, w2);
  cf w5 = cmul(w3, w2);
  cf w6 = cmul(w3, w3);
  cf w7 = cmul(w4, w3);
  x[4] = cmul(x[4], w4); x[5] = cmul(x[5], w5); x[6] = cmul(x[6], w6);
  x[7] = cmul(x[7], w7);
}

// table-based chains: forward (x *= t) and inverse (x *= conj(t))
__device__ __forceinline__ void chain8f(cf x[8], const cf t[7]){
  #pragma unroll
  for (int k = 0; k < 7; ++k) x[k+1] = cmul(x[k+1], t[k]);
}
__device__ __forceinline__ void chain8i(cf x[8], const cf t[7]){
  #pragma unroll
  for (int k = 0; k < 7; ++k) x[k+1] = cmulc(x[k+1], t[k]);
}

// omega16 twiddle: x[d] *= omega16^{S*t000*d}
__device__ __forceinline__ constexpr float c16t(int d){
  return (d==1)?0.92387953251128675613f:(d==2)?0.70710678118654752440f:
         (d==3)?0.38268343236508977173f:(d==4)?0.f:
         (d==5)?-0.38268343236508977173f:(d==6)?-0.70710678118654752440f:
         -0.92387953251128675613f;
}
__device__ __forceinline__ constexpr float s16t(int d){
  return (d==1)?0.38268343236508977173f:(d==2)?0.70710678118654752440f:
         (d==3)?0.92387953251128675613f:(d==4)?1.f:
         (d==5)?0.92387953251128675613f:(d==6)?0.70710678118654752440f:
         0.38268343236508977173f;
}
template<int S>
__device__ __forceinline__ void tw16(cf x[8], int t000){
  #pragma unroll
  for (int d = 1; d < 8; ++d) {
    float ce = t000 ? c16t(d) : 1.f;
    float se = t000 ? ((S < 0) ? -s16t(d) : s16t(d)) : 0.f;
    cf a = x[d];
    x[d] = make_float2(a.x*ce - a.y*se, a.x*se + a.y*ce);
  }
}

__device__ __forceinline__ void r2_shfl(cf x[8], int tid){
  const float sgn = (tid & 1) ? -1.f : 1.f;
  #pragma unroll
  for (int k = 0; k < 8; ++k) {
    float ox = __shfl_xor(x[k].x, 1, 64);
    float oy = __shfl_xor(x[k].y, 1, 64);
    x[k].x = ox + sgn * x[k].x;
    x[k].y = oy + sgn * x[k].y;
  }
}

// ---------------------------------------------------------------- k_at (fp64 setup)
__global__ __launch_bounds__(256) void k_at(
    const float* __restrict__ Lam_ri, const float* __restrict__ p_ri,
    const float* __restrict__ q_ri,  const float* __restrict__ Vc_ri,
    const float* __restrict__ Ct_ri, const float* __restrict__ Bp,
    const float* __restrict__ log_step, float2* __restrict__ atroots) {
  __shared__ double2 lam[NST], ctB[NST], ctp[NST], qB[NST], qp[NST];
  __shared__ double stepd;
  int tx = threadIdx.x;
  if (tx < NST) {
    int n = tx;
    double lr = Lam_ri[2*n], li = Lam_ri[2*n+1];
    double pr = p_ri[2*n],  pi = p_ri[2*n+1];
    double qr = q_ri[2*n],  qi = q_ri[2*n+1];
    double cr = Ct_ri[2*n], ci = Ct_ri[2*n+1];
    double br = 0.0, bi = 0.0;
    for (int m = 0; m < NST; ++m) {
      double b = (double)Bp[m];
      br += (double)Vc_ri[2*(n*NST+m)]   * b;
      bi += (double)Vc_ri[2*(n*NST+m)+1] * b;
    }
    lam[n] = make_double2(lr, li);
    ctB[n] = make_double2(cr*br + ci*bi, cr*bi - ci*br);
    ctp[n] = make_double2(cr*pr + ci*pi, cr*pi - ci*pr);
    qB[n]  = make_double2(qr*br + qi*bi, qr*bi - qi*br);
    qp[n]  = make_double2(qr*pr + qi*pi, qr*pi - qi*pr);
  }
  if (tx == 0) stepd = exp((double)log_step[0]);
  __syncthreads();
  int l = blockIdx.x * 256 + tx;
  double ang = -2.0 * M_PI * (double)l / (double)SEQ_L;
  double sn, cs;
  sincos(ang, &sn, &cs);
  double2 onem = make_double2(1.0 - cs, -sn);
  double2 onep = make_double2(1.0 + cs,  sn);
  double den = onep.x*onep.x + onep.y*onep.y;
  double2 ip = make_double2(onep.x/den, -onep.y/den);
  double2 g  = dcmul(onem, ip);
  double tw = 2.0 / stepd;
  g.x *= tw; g.y *= tw;
  double2 cc = make_double2(2.0*ip.x, 2.0*ip.y);
  double2 k00 = make_double2(0,0), k01 = make_double2(0,0);
  double2 k10 = make_double2(0,0), k11 = make_double2(0,0);
  for (int n = 0; n < NST; ++n) {
    double2 L = lam[n];
    double2 d = make_double2(g.x - L.x, g.y - L.y);
    double dd = d.x*d.x + d.y*d.y;
    double2 inv = make_double2(d.x/dd, -d.y/dd);
    double2 v;
    v = ctB[n]; k00.x += v.x*inv.x - v.y*inv.y; k00.y += v.x*inv.y + v.y*inv.x;
    v = ctp[n]; k01.x += v.x*inv.x - v.y*inv.y; k01.y += v.x*inv.y + v.y*inv.x;
    v = qB[n];  k10.x += v.x*inv.x - v.y*inv.y; k10.y += v.x*inv.y + v.y*inv.x;
    v = qp[n];  k11.x += v.x*inv.x - v.y*inv.y; k11.y += v.x*inv.y + v.y*inv.x;
  }
  double2 k11p = make_double2(1.0 + k11.x, k11.y);
  double2 num  = dcmul(k01, k10);
  double dd2 = k11p.x*k11p.x + k11p.y*k11p.y;
  double2 t = make_double2((num.x*k11p.x + num.y*k11p.y)/dd2,
                           (num.y*k11p.x - num.x*k11p.y)/dd2);
  double2 inner = make_double2(k00.x - t.x, k00.y - t.y);
  double2 at = dcmul(cc, inner);
  atroots[l] = make_float2((float)at.x, (float)at.y);
}

// ---------------------------------------------------------------- k_Gab (one block, 1024 thr)
// Phase 1 (tid<512): Kt = Re(IDFT_4096(at))/4096 via S=+1 forward structure.
// Phase 2 (all):     G  = FFT_8192([Kt,0]), natural order bins 0..4096, in LDS.
// Phase 3 (all):     ab[idx] for k_conv's permuted bin order.
// Phase 4 (all):     twiddle tables T1/T2/T3 for k_conv (double-precision gen).
__global__ __launch_bounds__(1024) void k_Gab(const float2* __restrict__ at,
                                              float4* __restrict__ ab,
                                              float2* __restrict__ tw1,
                                              float2* __restrict__ tw2,
                                              float2* __restrict__ tw3) {
  __shared__ cf lds8[NFFT];                 // 64 KB, reused across phases
  float* ktf = (float*)(lds8 + 4096);       // 4096 floats in cf[4096..6143]
  const int tid = threadIdx.x;
  const bool act = tid < 512;
  const int a14 = tid >> 6, t04 = tid & 63, b24 = (tid >> 3) & 7, t004 = tid & 7;
  cf x[8];

  // ---- phase 1: forward-structure FFT_4096 with S=+1 on at (natural in)
  if (act) {
    #pragma unroll
    for (int m = 0; m < 8; ++m) x[m] = at[tid + 512*m];
    dft8<1, false>(x);
    chain8(x, TWO_PI * (float)tid / (float)M4);
    #pragma unroll
    for (int a = 0; a < 8; ++a) lds8[a*512 + tid] = x[a];
  }
  __syncthreads();
  if (act) {
    #pragma unroll
    for (int r = 0; r < 8; ++r) x[r] = lds8[a14*512 + t04 + 64*r];
    dft8<1, false>(x);
    chain8(x, TWO_PI * (float)t04 / 512.f);
  }
  __syncthreads();
  if (act) {
    #pragma unroll
    for (int b = 0; b < 8; ++b) lds8[s2f(a14*512 + b*64 + t04)] = x[b];
  }
  __syncthreads();
  if (act) {
    #pragma unroll
    for (int r = 0; r < 8; ++r) x[r] = lds8[s2f(a14*512 + b24*64 + t004 + 8*r)];
    dft8<1, false>(x);
    chain8(x, TWO_PI * (float)t004 / 64.f);
  }
  __syncthreads();
  if (act) {
    #pragma unroll
    for (int c = 0; c < 8; ++c) lds8[s3f(a14*512 + b24*64 + c*8 + t004)] = x[c];
  }
  __syncthreads();
  if (act) {
    #pragma unroll
    for (int r = 0; r < 8; ++r) x[r] = lds8[s3f(a14*512 + b24*64 + t004*8 + r)];
    dft8<1, false>(x);            // slot d holds time index t = a14+8*b24+64*t004+512*d
    const int tb = a14 + 8*b24 + 64*t004;
    #pragma unroll
    for (int d = 0; d < 8; ++d) ktf[tb + 512*d] = x[d].x * (1.f/(float)M4);
  }
  __syncthreads();

  // ---- phase 2: FFT_8192([Kt,0])
  {
    const int a1 = tid >> 7, t0 = tid & 127, b2 = (tid >> 4) & 7, t00 = tid & 15;
    const int c3 = (tid >> 1) & 7, t000 = tid & 1;
    #pragma unroll
    for (int m = 0; m < 4; ++m) x[m] = make_float2(ktf[tid + 1024*m], 0.f);
    #pragma unroll
    for (int m = 4; m < 8; ++m) x[m] = make_float2(0.f, 0.f);
    dft8<-1, true>(x);
    chain8(x, -TWO_PI * (float)tid / (float)NFFT);
    __syncthreads();
    #pragma unroll
    for (int a = 0; a < 8; ++a) lds8[sw(a*1024 + tid)] = x[a];
    __syncthreads();
    #pragma unroll
    for (int r = 0; r < 8; ++r) x[r] = lds8[sw(a1*1024 + t0 + 128*r)];
    dft8<-1, false>(x);
    chain8(x, -TWO_PI * (float)t0 / 1024.f);
    __syncthreads();
    #pragma unroll
    for (int b = 0; b < 8; ++b) lds8[sw(a1*1024 + b*128 + t0)] = x[b];
    __syncthreads();
    #pragma unroll
    for (int r = 0; r < 8; ++r) x[r] = lds8[sw(a1*1024 + b2*128 + t00 + 16*r)];
    dft8<-1, false>(x);
    chain8(x, -TWO_PI * (float)t00 / 128.f);
    __syncthreads();
    #pragma unroll
    for (int c = 0; c < 8; ++c) lds8[sw(a1*1024 + b2*128 + c*16 + t00)] = x[c];
    __syncthreads();
    #pragma unroll
    for (int r = 0; r < 8; ++r) x[r] = lds8[sw(a1*1024 + b2*128 + c3*16 + t000 + 2*r)];
    dft8<-1, false>(x);
    tw16<-1>(x, t000);
    r2_shfl(x, tid);
    __syncthreads();
    #pragma unroll
    for (int d = 0; d < 8; ++d) {
      int bin = a1 + 8*b2 + 64*c3 + 512*d + 4096*t000;
      if (bin <= M4) lds8[bin] = x[d];     // G natural order, bins 0..4096
    }
  }
  __syncthreads();

  // ---- phase 3: ab (4 bins per thread)
  #pragma unroll
  for (int j = 0; j < 4; ++j) {
    int idx = tid * 4 + j;                  // 0..4095
    int tidc = idx >> 3, d = idx & 7;
    int k = (tidc >> 6) + 8*((tidc >> 3) & 7) + 64*(tidc & 7) + 512*d;
    double ang = -2.0 * M_PI * (double)k / (double)NFFT;
    double sn, cs; sincos(ang, &sn, &cs);        // E = (cs, sn)
    double2 a = make_double2(0.5*(1.0 + sn), -0.5*cs);
    double2 b = make_double2(0.5*(1.0 - sn),  0.5*cs);
    double2 p = make_double2(0.5*(1.0 + sn),  0.5*cs);
    double2 q = make_double2(0.5*(1.0 - sn), -0.5*cs);
    cf gk = lds8[k];
    cf gh = lds8[M4 - k];
    double2 Gk = make_double2(gk.x, gk.y);
    double2 Gh = make_double2(gh.x, -gh.y);      // conj
    double2 pa = dcmul(p, a), pb = dcmul(p, b);
    double2 qa = dcmul(q, a), qb = dcmul(q, b);
    double2 al = dcmul(pa, Gk), t1 = dcmul(qb, Gh);
    al.x += t1.x; al.y += t1.y;
    double2 be = dcmul(pb, Gk), t2 = dcmul(qa, Gh);
    be.x += t2.x; be.y += t2.y;
    const double s = 1.0 / (double)M4;
    ab[idx] = make_float4((float)(al.x*s), (float)(al.y*s),
                          (float)(be.x*s), (float)(be.y*s));
  }

  // ---- phase 4: twiddle tables (independent of LDS; no barrier needed)
  // T1[k*512+j] = exp(-2pi i j(k+1)/4096), T2[k*64+j] = exp(-2pi i j(k+1)/512),
  // T3[k*8+j]   = exp(-2pi i j(k+1)/64)
  for (int i = tid; i < 7*512; i += 1024) {
    int k = i >> 9, j = i & 511;
    double an = -2.0 * M_PI * (double)(j*(k+1)) / 4096.0;
    double sn, cs; sincos(an, &sn, &cs);
    tw1[i] = make_float2((float)cs, (float)sn);
  }
  if (tid < 7*64) {
    int k = tid >> 6, j = tid & 63;
    double an = -2.0 * M_PI * (double)(j*(k+1)) / 512.0;
    double sn, cs; sincos(an, &sn, &cs);
    tw2[tid] = make_float2((float)cs, (float)sn);
  }
  if (tid < 7*8) {
    int k = tid >> 3, j = tid & 7;
    double an = -2.0 * M_PI * (double)(j*(k+1)) / 64.0;
    double sn, cs; sincos(an, &sn, &cs);
    tw3[tid] = make_float2((float)cs, (float)sn);
  }
}

// ---------------------------------------------------------------- k_conv (one row per block)
// r6 structure byte-for-byte except twiddles come from tables:
// T1 (global->regs, conj-reused), T2/T3 (LDS). Same barriers/swizzles/dft8.
__global__ __launch_bounds__(512) void k_conv(const float* __restrict__ u,
                                              const float4* __restrict__ ab,
                                              const float2* __restrict__ tw1,
                                              const float2* __restrict__ tw2,
                                              const float2* __restrict__ tw3,
                                              const float* __restrict__ Dp,
                                              float* __restrict__ out) {
  __shared__ cf lds[M4];
  __shared__ cf sT2[7*64];
  __shared__ cf sT3[7*8];
  const int tid = threadIdx.x;
  const size_t row = blockIdx.x;
  const float2* ru = (const float2*)(u + row * SEQ_L);
  const int a1 = tid >> 6, t0 = tid & 63, b2 = (tid >> 3) & 7, t00 = tid & 7;

  // preload tables: T1 -> regs (held through kernel), T2/T3 -> LDS
  cf t1[7];
  #pragma unroll
  for (int k = 0; k < 7; ++k) t1[k] = tw1[k*512 + tid];
  if (tid < 7*64) sT2[tid] = tw2[tid];
  if (tid < 7*8)  sT3[tid] = tw3[tid];

  cf x[8];
  #pragma unroll
  for (int m = 0; m < 4; ++m) { float2 v = ru[tid + 512*m]; x[m] = make_float2(v.x, v.y); }
  #pragma unroll
  for (int m = 4; m < 8; ++m) x[m] = make_float2(0.f, 0.f);

  // ---- forward FFT_4096 (DIF, digits a,b,c,d)
  dft8<-1, true>(x);
  chain8f(x, t1);
  #pragma unroll
  for (int a = 0; a < 8; ++a) lds[a*512 + tid] = x[a];
  __syncthreads();
  #pragma unroll
  for (int r = 0; r < 8; ++r) x[r] = lds[a1*512 + t0 + 64*r];
  dft8<-1, false>(x);
  { cf t[7];
    #pragma unroll
    for (int k = 0; k < 7; ++k) t[k] = sT2[k*64 + t0];
    chain8f(x, t); }
  __syncthreads();
  #pragma unroll
  for (int b = 0; b < 8; ++b) lds[s2f(a1*512 + b*64 + t0)] = x[b];
  __syncthreads();
  #pragma unroll
  for (int r = 0; r < 8; ++r) x[r] = lds[s2f(a1*512 + b2*64 + t00 + 8*r)];
  dft8<-1, false>(x);
  { cf t[7];
    #pragma unroll
    for (int k = 0; k < 7; ++k) t[k] = sT3[k*8 + t00];
    chain8f(x, t); }
  __syncthreads();
  #pragma unroll
  for (int c = 0; c < 8; ++c) lds[s3f(a1*512 + b2*64 + c*8 + t00)] = x[c];
  __syncthreads();
  #pragma unroll
  for (int r = 0; r < 8; ++r) x[r] = lds[s3f(a1*512 + b2*64 + t00*8 + r)];
  dft8<-1, false>(x);            // slot d holds bin k = a1 + 8*b2 + 64*t00 + 512*d
  __syncthreads();

  // ---- mid: Z'[k] = alpha*Z[k] + beta*conj(Z[4096-k])
  const int base = a1 + 8*b2 + 64*t00;
  #pragma unroll
  for (int d = 0; d < 8; ++d) lds[smf(base + 512*d)] = x[d];
  __syncthreads();
  const float4* abp = ab + (size_t)tid * 8;
  #pragma unroll
  for (int d = 0; d < 8; ++d) {
    cf t = lds[smf((M4 - base - 512*d) & (M4 - 1))];
    float4 c = abp[d];
    x[d] = make_float2(c.x*x[d].x - c.y*x[d].y + c.z*t.x + c.w*t.y,
                       c.x*x[d].y + c.y*x[d].x + c.w*t.x - c.z*t.y);
  }
  __syncthreads();

  // ---- inverse FFT_4096 (exact mirror; 1/4096 folded into ab)
  dft8<1, false>(x);
  #pragma unroll
  for (int r = 0; r < 8; ++r) lds[s3f(a1*512 + b2*64 + t00*8 + r)] = x[r];
  __syncthreads();
  #pragma unroll
  for (int c = 0; c < 8; ++c) x[c] = lds[s3f(a1*512 + b2*64 + c*8 + t00)];
  { cf t[7];
    #pragma unroll
    for (int k = 0; k < 7; ++k) t[k] = sT3[k*8 + t00];
    chain8i(x, t); }
  dft8<1, false>(x);
  __syncthreads();
  #pragma unroll
  for (int r = 0; r < 8; ++r) lds[s2f(a1*512 + b2*64 + t00 + 8*r)] = x[r];
  __syncthreads();
  #pragma unroll
  for (int b = 0; b < 8; ++b) x[b] = lds[s2f(a1*512 + b*64 + t0)];
  { cf t[7];
    #pragma unroll
    for (int k = 0; k < 7; ++k) t[k] = sT2[k*64 + t0];
    chain8i(x, t); }
  dft8<1, false>(x);
  __syncthreads();
  #pragma unroll
  for (int r = 0; r < 8; ++r) lds[a1*512 + t0 + 64*r] = x[r];
  __syncthreads();
  #pragma unroll
  for (int a = 0; a < 8; ++a) x[a] = lds[a*512 + tid];
  chain8i(x, t1);
  dft8<1, false, true>(x);       // only x[0..3] needed (n < 2048)

  // ---- epilogue: y[2n]=Re, y[2n+1]=Im, + D*u
  const float Dv = Dp[0];
  float2* o = (float2*)(out + row * SEQ_L);
  #pragma unroll
  for (int m = 0; m < 4; ++m) {
    float2 uv = ru[tid + 512*m];
    o[tid + 512*m] = make_float2(x[m].x + Dv*uv.x, x[m].y + Dv*uv.y);
  }
}

// ---------------------------------------------------------------- launch
extern "C" void kernel_launch(void* const* d_in, const int* in_sizes, int n_in,
                              void* d_out, int out_size, void* d_ws, size_t ws_size,
                              hipStream_t stream) {
  const float* u      = (const float*)d_in[0];
  const float* Lam_ri = (const float*)d_in[1];
  const float* p_ri   = (const float*)d_in[2];
  const float* q_ri   = (const float*)d_in[3];
  const float* Vc_ri  = (const float*)d_in[4];
  const float* Ct_ri  = (const float*)d_in[5];
  const float* Bp     = (const float*)d_in[6];
  const float* Dp     = (const float*)d_in[7];
  const float* ls     = (const float*)d_in[8];

  char* ws = (char*)d_ws;
  float2* atroots = (float2*)(ws);             // 32768 B
  float4* ab      = (float4*)(ws + 32768);     // 65536 B (permuted order)
  float2* tw1     = (float2*)(ws + 98304);     // 28672 B
  float2* tw2     = (float2*)(ws + 126976);    // 3584 B
  float2* tw3     = (float2*)(ws + 130560);    // 448 B

  k_at  <<<dim3(SEQ_L/256), dim3(256), 0, stream>>>(Lam_ri, p_ri, q_ri, Vc_ri, Ct_ri, Bp, ls, atroots);
  k_Gab <<<dim3(1),    dim3(1024), 0, stream>>>(atroots, ab, tw1, tw2, tw3);
  k_conv<<<dim3(NROWS), dim3(512), 0, stream>>>(u, ab, tw1, tw2, tw3, Dp, (float*)d_out);
}

// Round 13
// 183.893 us; speedup vs baseline: 1.0669x; 1.0669x over previous
//
#include <hip/hip_runtime.h>
#include <math.h>

// S4 conv: y = irfft(rfft(u,8192)*rfft(K,8192))[:4096] + D*u ; K shared by all rows.
// Round 13: revert to round-11 exactly (best measured: 184.8us total).
// k_conv is the r6 structure (170.5us, reproduced 4x) — six attempted
// optimizations of it all regressed (barrier-thinning, pack-math, twiddle
// tables, larger blocks). Prep = k_at + fused single-block k_Gab.

#define SEQ_L 4096
#define M4    4096
#define NFFT  8192
#define NST   64
#define NROWS 8192
#define TWO_PI 6.28318530717958647692f

typedef float2 cf;

__device__ __forceinline__ cf cmul(cf a, cf b){ return make_float2(a.x*b.x - a.y*b.y, a.x*b.y + a.y*b.x); }
__device__ __forceinline__ cf cadd(cf a, cf b){ return make_float2(a.x+b.x, a.y+b.y); }
__device__ __forceinline__ cf csub(cf a, cf b){ return make_float2(a.x-b.x, a.y-b.y); }
__device__ __forceinline__ double2 dcmul(double2 a, double2 b) {
  return make_double2(a.x*b.x - a.y*b.y, a.x*b.y + a.y*b.x);
}

// k_conv / phase-1 swizzles (4096-cf space); involutions
__device__ __forceinline__ int s2f(int i){ return i ^ (((i >> 6) & 1) << 3); }
__device__ __forceinline__ int s3f(int i){ return i ^ ((i >> 6) & 7) ^ (((i >> 6) & 1) << 3); }
__device__ __forceinline__ int smf(int i){ return i ^ ((i >> 6) & 7); }
// phase-2 swizzle (8192-cf space)
__device__ __forceinline__ int sw(int p){ return p ^ ((p >> 4) & 15); }

template<int S>
__device__ __forceinline__ void r4(cf& a0, cf& a1, cf& a2, cf& a3){
  cf t0 = cadd(a0,a2), t1 = csub(a0,a2);
  cf t2 = cadd(a1,a3), t3 = csub(a1,a3);
  cf w = (S < 0) ? make_float2(t3.y, -t3.x) : make_float2(-t3.y, t3.x);
  a0 = cadd(t0,t2); a2 = csub(t0,t2);
  a1 = cadd(t1,w);  a3 = csub(t1,w);
}

template<int S, bool ZHI, bool LO4=false>
__device__ __forceinline__ void dft8(cf x[8]){
  const float C = 0.70710678118654752f;
  cf e0,e1,e2,e3,o0,o1,o2,o3;
  if (ZHI) {
    cf w  = (S<0)? make_float2(x[2].y,-x[2].x) : make_float2(-x[2].y,x[2].x);
    e0 = cadd(x[0],x[2]); e2 = csub(x[0],x[2]);
    e1 = cadd(x[0],w);    e3 = csub(x[0],w);
    cf w2 = (S<0)? make_float2(x[3].y,-x[3].x) : make_float2(-x[3].y,x[3].x);
    o0 = cadd(x[1],x[3]); o2 = csub(x[1],x[3]);
    o1 = cadd(x[1],w2);   o3 = csub(x[1],w2);
  } else {
    cf a0=x[0],a1=x[2],a2=x[4],a3=x[6];
    r4<S>(a0,a1,a2,a3);  e0=a0;e1=a1;e2=a2;e3=a3;
    cf b0=x[1],b1=x[3],b2=x[5],b3=x[7];
    r4<S>(b0,b1,b2,b3);  o0=b0;o1=b1;o2=b2;o3=b3;
  }
  x[0] = cadd(e0,o0); if (!LO4) x[4] = csub(e0,o0);
  cf t1 = (S<0)? make_float2(C*(o1.x+o1.y), C*(o1.y-o1.x))
               : make_float2(C*(o1.x-o1.y), C*(o1.x+o1.y));
  x[1] = cadd(e1,t1); if (!LO4) x[5] = csub(e1,t1);
  cf t2 = (S<0)? make_float2(o2.y,-o2.x) : make_float2(-o2.y,o2.x);
  x[2] = cadd(e2,t2); if (!LO4) x[6] = csub(e2,t2);
  cf t3 = (S<0)? make_float2(C*(o3.y-o3.x), -C*(o3.x+o3.y))
               : make_float2(-C*(o3.x+o3.y), C*(o3.x-o3.y));
  x[3] = cadd(e3,t3); if (!LO4) x[7] = csub(e3,t3);
}

__device__ __forceinline__ void chain8(cf x[8], float th){
  float sn, cs; __sincosf(th, &sn, &cs);
  cf w1 = make_float2(cs, sn);
  cf w2 = cmul(w1, w1);
  cf w3 = cmul(w2, w1);
  x[1] = cmul(x[1], w1); x[2] = cmul(x[2], w2); x[3] = cmul(x[3], w3);
  cf w4 = cmul(w2, w2);
  cf w5 = cmul(w3, w2);
  cf w6 = cmul(w3, w3);
  cf w7 = cmul(w4, w3);
  x[4] = cmul(x[4], w4); x[5] = cmul(x[5], w5); x[6] = cmul(x[6], w6);
  x[7] = cmul(x[7], w7);
}

// omega16 twiddle: x[d] *= omega16^{S*t000*d}
__device__ __forceinline__ constexpr float c16t(int d){
  return (d==1)?0.92387953251128675613f:(d==2)?0.70710678118654752440f:
         (d==3)?0.38268343236508977173f:(d==4)?0.f:
         (d==5)?-0.38268343236508977173f:(d==6)?-0.70710678118654752440f:
         -0.92387953251128675613f;
}
__device__ __forceinline__ constexpr float s16t(int d){
  return (d==1)?0.38268343236508977173f:(d==2)?0.70710678118654752440f:
         (d==3)?0.92387953251128675613f:(d==4)?1.f:
         (d==5)?0.92387953251128675613f:(d==6)?0.70710678118654752440f:
         0.38268343236508977173f;
}
template<int S>
__device__ __forceinline__ void tw16(cf x[8], int t000){
  #pragma unroll
  for (int d = 1; d < 8; ++d) {
    float ce = t000 ? c16t(d) : 1.f;
    float se = t000 ? ((S < 0) ? -s16t(d) : s16t(d)) : 0.f;
    cf a = x[d];
    x[d] = make_float2(a.x*ce - a.y*se, a.x*se + a.y*ce);
  }
}

__device__ __forceinline__ void r2_shfl(cf x[8], int tid){
  const float sgn = (tid & 1) ? -1.f : 1.f;
  #pragma unroll
  for (int k = 0; k < 8; ++k) {
    float ox = __shfl_xor(x[k].x, 1, 64);
    float oy = __shfl_xor(x[k].y, 1, 64);
    x[k].x = ox + sgn * x[k].x;
    x[k].y = oy + sgn * x[k].y;
  }
}

// ---------------------------------------------------------------- k_at (fp64 setup)
__global__ __launch_bounds__(256) void k_at(
    const float* __restrict__ Lam_ri, const float* __restrict__ p_ri,
    const float* __restrict__ q_ri,  const float* __restrict__ Vc_ri,
    const float* __restrict__ Ct_ri, const float* __restrict__ Bp,
    const float* __restrict__ log_step, float2* __restrict__ atroots) {
  __shared__ double2 lam[NST], ctB[NST], ctp[NST], qB[NST], qp[NST];
  __shared__ double stepd;
  int tx = threadIdx.x;
  if (tx < NST) {
    int n = tx;
    double lr = Lam_ri[2*n], li = Lam_ri[2*n+1];
    double pr = p_ri[2*n],  pi = p_ri[2*n+1];
    double qr = q_ri[2*n],  qi = q_ri[2*n+1];
    double cr = Ct_ri[2*n], ci = Ct_ri[2*n+1];
    double br = 0.0, bi = 0.0;
    for (int m = 0; m < NST; ++m) {
      double b = (double)Bp[m];
      br += (double)Vc_ri[2*(n*NST+m)]   * b;
      bi += (double)Vc_ri[2*(n*NST+m)+1] * b;
    }
    lam[n] = make_double2(lr, li);
    ctB[n] = make_double2(cr*br + ci*bi, cr*bi - ci*br);
    ctp[n] = make_double2(cr*pr + ci*pi, cr*pi - ci*pr);
    qB[n]  = make_double2(qr*br + qi*bi, qr*bi - qi*br);
    qp[n]  = make_double2(qr*pr + qi*pi, qr*pi - qi*pr);
  }
  if (tx == 0) stepd = exp((double)log_step[0]);
  __syncthreads();
  int l = blockIdx.x * 256 + tx;
  double ang = -2.0 * M_PI * (double)l / (double)SEQ_L;
  double sn, cs;
  sincos(ang, &sn, &cs);
  double2 onem = make_double2(1.0 - cs, -sn);
  double2 onep = make_double2(1.0 + cs,  sn);
  double den = onep.x*onep.x + onep.y*onep.y;
  double2 ip = make_double2(onep.x/den, -onep.y/den);
  double2 g  = dcmul(onem, ip);
  double tw = 2.0 / stepd;
  g.x *= tw; g.y *= tw;
  double2 cc = make_double2(2.0*ip.x, 2.0*ip.y);
  double2 k00 = make_double2(0,0), k01 = make_double2(0,0);
  double2 k10 = make_double2(0,0), k11 = make_double2(0,0);
  for (int n = 0; n < NST; ++n) {
    double2 L = lam[n];
    double2 d = make_double2(g.x - L.x, g.y - L.y);
    double dd = d.x*d.x + d.y*d.y;
    double2 inv = make_double2(d.x/dd, -d.y/dd);
    double2 v;
    v = ctB[n]; k00.x += v.x*inv.x - v.y*inv.y; k00.y += v.x*inv.y + v.y*inv.x;
    v = ctp[n]; k01.x += v.x*inv.x - v.y*inv.y; k01.y += v.x*inv.y + v.y*inv.x;
    v = qB[n];  k10.x += v.x*inv.x - v.y*inv.y; k10.y += v.x*inv.y + v.y*inv.x;
    v = qp[n];  k11.x += v.x*inv.x - v.y*inv.y; k11.y += v.x*inv.y + v.y*inv.x;
  }
  double2 k11p = make_double2(1.0 + k11.x, k11.y);
  double2 num  = dcmul(k01, k10);
  double dd2 = k11p.x*k11p.x + k11p.y*k11p.y;
  double2 t = make_double2((num.x*k11p.x + num.y*k11p.y)/dd2,
                           (num.y*k11p.x - num.x*k11p.y)/dd2);
  double2 inner = make_double2(k00.x - t.x, k00.y - t.y);
  double2 at = dcmul(cc, inner);
  atroots[l] = make_float2((float)at.x, (float)at.y);
}

// ---------------------------------------------------------------- k_Gab (one block, 1024 thr)
// Phase 1 (tid<512): Kt = Re(IDFT_4096(at))/4096 via S=+1 forward structure.
// Phase 2 (all):     G  = FFT_8192([Kt,0]), natural order bins 0..4096, in LDS.
// Phase 3 (all):     ab[idx] for k_conv's permuted bin order.
__global__ __launch_bounds__(1024) void k_Gab(const float2* __restrict__ at,
                                              float4* __restrict__ ab) {
  __shared__ cf lds8[NFFT];                 // 64 KB, reused across phases
  float* ktf = (float*)(lds8 + 4096);       // 4096 floats in cf[4096..6143]
  const int tid = threadIdx.x;
  const bool act = tid < 512;
  const int a14 = tid >> 6, t04 = tid & 63, b24 = (tid >> 3) & 7, t004 = tid & 7;
  cf x[8];

  // ---- phase 1: forward-structure FFT_4096 with S=+1 on at (natural in)
  if (act) {
    #pragma unroll
    for (int m = 0; m < 8; ++m) x[m] = at[tid + 512*m];
    dft8<1, false>(x);
    chain8(x, TWO_PI * (float)tid / (float)M4);
    #pragma unroll
    for (int a = 0; a < 8; ++a) lds8[a*512 + tid] = x[a];
  }
  __syncthreads();
  if (act) {
    #pragma unroll
    for (int r = 0; r < 8; ++r) x[r] = lds8[a14*512 + t04 + 64*r];
    dft8<1, false>(x);
    chain8(x, TWO_PI * (float)t04 / 512.f);
  }
  __syncthreads();
  if (act) {
    #pragma unroll
    for (int b = 0; b < 8; ++b) lds8[s2f(a14*512 + b*64 + t04)] = x[b];
  }
  __syncthreads();
  if (act) {
    #pragma unroll
    for (int r = 0; r < 8; ++r) x[r] = lds8[s2f(a14*512 + b24*64 + t004 + 8*r)];
    dft8<1, false>(x);
    chain8(x, TWO_PI * (float)t004 / 64.f);
  }
  __syncthreads();
  if (act) {
    #pragma unroll
    for (int c = 0; c < 8; ++c) lds8[s3f(a14*512 + b24*64 + c*8 + t004)] = x[c];
  }
  __syncthreads();
  if (act) {
    #pragma unroll
    for (int r = 0; r < 8; ++r) x[r] = lds8[s3f(a14*512 + b24*64 + t004*8 + r)];
    dft8<1, false>(x);            // slot d holds time index t = a14+8*b24+64*t004+512*d
    const int tb = a14 + 8*b24 + 64*t004;
    #pragma unroll
    for (int d = 0; d < 8; ++d) ktf[tb + 512*d] = x[d].x * (1.f/(float)M4);
  }
  __syncthreads();

  // ---- phase 2: FFT_8192([Kt,0]) (r9 k_G structure, input/out via LDS)
  {
    const int a1 = tid >> 7, t0 = tid & 127, b2 = (tid >> 4) & 7, t00 = tid & 15;
    const int c3 = (tid >> 1) & 7, t000 = tid & 1;
    #pragma unroll
    for (int m = 0; m < 4; ++m) x[m] = make_float2(ktf[tid + 1024*m], 0.f);
    #pragma unroll
    for (int m = 4; m < 8; ++m) x[m] = make_float2(0.f, 0.f);
    dft8<-1, true>(x);
    chain8(x, -TWO_PI * (float)tid / (float)NFFT);
    __syncthreads();                       // all ktf reads done before overwrite
    #pragma unroll
    for (int a = 0; a < 8; ++a) lds8[sw(a*1024 + tid)] = x[a];
    __syncthreads();
    #pragma unroll
    for (int r = 0; r < 8; ++r) x[r] = lds8[sw(a1*1024 + t0 + 128*r)];
    dft8<-1, false>(x);
    chain8(x, -TWO_PI * (float)t0 / 1024.f);
    __syncthreads();
    #pragma unroll
    for (int b = 0; b < 8; ++b) lds8[sw(a1*1024 + b*128 + t0)] = x[b];
    __syncthreads();
    #pragma unroll
    for (int r = 0; r < 8; ++r) x[r] = lds8[sw(a1*1024 + b2*128 + t00 + 16*r)];
    dft8<-1, false>(x);
    chain8(x, -TWO_PI * (float)t00 / 128.f);
    __syncthreads();
    #pragma unroll
    for (int c = 0; c < 8; ++c) lds8[sw(a1*1024 + b2*128 + c*16 + t00)] = x[c];
    __syncthreads();
    #pragma unroll
    for (int r = 0; r < 8; ++r) x[r] = lds8[sw(a1*1024 + b2*128 + c3*16 + t000 + 2*r)];
    dft8<-1, false>(x);
    tw16<-1>(x, t000);
    r2_shfl(x, tid);
    __syncthreads();                       // exchange reads done before G write
    #pragma unroll
    for (int d = 0; d < 8; ++d) {
      int bin = a1 + 8*b2 + 64*c3 + 512*d + 4096*t000;
      if (bin <= M4) lds8[bin] = x[d];     // G natural order, bins 0..4096
    }
  }
  __syncthreads();

  // ---- phase 3: ab (r9 k_ab math), 4 bins per thread
  #pragma unroll
  for (int j = 0; j < 4; ++j) {
    int idx = tid * 4 + j;                  // 0..4095
    int tidc = idx >> 3, d = idx & 7;
    int k = (tidc >> 6) + 8*((tidc >> 3) & 7) + 64*(tidc & 7) + 512*d;
    double ang = -2.0 * M_PI * (double)k / (double)NFFT;
    double sn, cs; sincos(ang, &sn, &cs);        // E = (cs, sn)
    double2 a = make_double2(0.5*(1.0 + sn), -0.5*cs);
    double2 b = make_double2(0.5*(1.0 - sn),  0.5*cs);
    double2 p = make_double2(0.5*(1.0 + sn),  0.5*cs);
    double2 q = make_double2(0.5*(1.0 - sn), -0.5*cs);
    cf gk = lds8[k];
    cf gh = lds8[M4 - k];
    double2 Gk = make_double2(gk.x, gk.y);
    double2 Gh = make_double2(gh.x, -gh.y);      // conj
    double2 pa = dcmul(p, a), pb = dcmul(p, b);
    double2 qa = dcmul(q, a), qb = dcmul(q, b);
    double2 al = dcmul(pa, Gk), t1 = dcmul(qb, Gh);
    al.x += t1.x; al.y += t1.y;
    double2 be = dcmul(pb, Gk), t2 = dcmul(qa, Gh);
    be.x += t2.x; be.y += t2.y;
    const double s = 1.0 / (double)M4;
    ab[idx] = make_float4((float)(al.x*s), (float)(al.y*s),
                          (float)(be.x*s), (float)(be.y*s));
  }
}

// ---------------------------------------------------------------- k_conv (one row per block)
// Verbatim round-6 version (best measured; 170.5us reproduced 4x).
__global__ __launch_bounds__(512) void k_conv(const float* __restrict__ u,
                                              const float4* __restrict__ ab,
                                              const float* __restrict__ Dp,
                                              float* __restrict__ out) {
  __shared__ cf lds[M4];
  const int tid = threadIdx.x;
  const size_t row = blockIdx.x;
  const float2* ru = (const float2*)(u + row * SEQ_L);
  const int a1 = tid >> 6, t0 = tid & 63, b2 = (tid >> 3) & 7, t00 = tid & 7;

  cf x[8];
  #pragma unroll
  for (int m = 0; m < 4; ++m) { float2 v = ru[tid + 512*m]; x[m] = make_float2(v.x, v.y); }
  #pragma unroll
  for (int m = 4; m < 8; ++m) x[m] = make_float2(0.f, 0.f);

  // ---- forward FFT_4096 (DIF, digits a,b,c,d)
  dft8<-1, true>(x);
  chain8(x, -TWO_PI * (float)tid / (float)M4);
  #pragma unroll
  for (int a = 0; a < 8; ++a) lds[a*512 + tid] = x[a];
  __syncthreads();
  #pragma unroll
  for (int r = 0; r < 8; ++r) x[r] = lds[a1*512 + t0 + 64*r];
  dft8<-1, false>(x);
  chain8(x, -TWO_PI * (float)t0 / 512.f);
  __syncthreads();
  #pragma unroll
  for (int b = 0; b < 8; ++b) lds[s2f(a1*512 + b*64 + t0)] = x[b];
  __syncthreads();
  #pragma unroll
  for (int r = 0; r < 8; ++r) x[r] = lds[s2f(a1*512 + b2*64 + t00 + 8*r)];
  dft8<-1, false>(x);
  chain8(x, -TWO_PI * (float)t00 / 64.f);
  __syncthreads();
  #pragma unroll
  for (int c = 0; c < 8; ++c) lds[s3f(a1*512 + b2*64 + c*8 + t00)] = x[c];
  __syncthreads();
  #pragma unroll
  for (int r = 0; r < 8; ++r) x[r] = lds[s3f(a1*512 + b2*64 + t00*8 + r)];
  dft8<-1, false>(x);            // slot d holds bin k = a1 + 8*b2 + 64*t00 + 512*d
  __syncthreads();

  // ---- mid: Z'[k] = alpha*Z[k] + beta*conj(Z[4096-k])
  const int base = a1 + 8*b2 + 64*t00;
  #pragma unroll
  for (int d = 0; d < 8; ++d) lds[smf(base + 512*d)] = x[d];
  __syncthreads();
  const float4* abp = ab + (size_t)tid * 8;
  #pragma unroll
  for (int d = 0; d < 8; ++d) {
    cf t = lds[smf((M4 - base - 512*d) & (M4 - 1))];
    float4 c = abp[d];
    x[d] = make_float2(c.x*x[d].x - c.y*x[d].y + c.z*t.x + c.w*t.y,
                       c.x*x[d].y + c.y*x[d].x + c.w*t.x - c.z*t.y);
  }
  __syncthreads();

  // ---- inverse FFT_4096 (exact mirror; 1/4096 folded into ab)
  dft8<1, false>(x);
  #pragma unroll
  for (int r = 0; r < 8; ++r) lds[s3f(a1*512 + b2*64 + t00*8 + r)] = x[r];
  __syncthreads();
  #pragma unroll
  for (int c = 0; c < 8; ++c) x[c] = lds[s3f(a1*512 + b2*64 + c*8 + t00)];
  chain8(x, TWO_PI * (float)t00 / 64.f);
  dft8<1, false>(x);
  __syncthreads();
  #pragma unroll
  for (int r = 0; r < 8; ++r) lds[s2f(a1*512 + b2*64 + t00 + 8*r)] = x[r];
  __syncthreads();
  #pragma unroll
  for (int b = 0; b < 8; ++b) x[b] = lds[s2f(a1*512 + b*64 + t0)];
  chain8(x, TWO_PI * (float)t0 / 512.f);
  dft8<1, false>(x);
  __syncthreads();
  #pragma unroll
  for (int r = 0; r < 8; ++r) lds[a1*512 + t0 + 64*r] = x[r];
  __syncthreads();
  #pragma unroll
  for (int a = 0; a < 8; ++a) x[a] = lds[a*512 + tid];
  chain8(x, TWO_PI * (float)tid / (float)M4);
  dft8<1, false, true>(x);       // only x[0..3] needed (n < 2048)

  // ---- epilogue: y[2n]=Re, y[2n+1]=Im, + D*u
  const float Dv = Dp[0];
  float2* o = (float2*)(out + row * SEQ_L);
  #pragma unroll
  for (int m = 0; m < 4; ++m) {
    float2 uv = ru[tid + 512*m];
    o[tid + 512*m] = make_float2(x[m].x + Dv*uv.x, x[m].y + Dv*uv.y);
  }
}

// ---------------------------------------------------------------- launch
extern "C" void kernel_launch(void* const* d_in, const int* in_sizes, int n_in,
                              void* d_out, int out_size, void* d_ws, size_t ws_size,
                              hipStream_t stream) {
  const float* u      = (const float*)d_in[0];
  const float* Lam_ri = (const float*)d_in[1];
  const float* p_ri   = (const float*)d_in[2];
  const float* q_ri   = (const float*)d_in[3];
  const float* Vc_ri  = (const float*)d_in[4];
  const float* Ct_ri  = (const float*)d_in[5];
  const float* Bp     = (const float*)d_in[6];
  const float* Dp     = (const float*)d_in[7];
  const float* ls     = (const float*)d_in[8];

  char* ws = (char*)d_ws;
  float2* atroots = (float2*)(ws);            // 32768 B
  float4* ab      = (float4*)(ws + 32768);    // 65536 B (permuted order)

  k_at  <<<dim3(SEQ_L/256), dim3(256), 0, stream>>>(Lam_ri, p_ri, q_ri, Vc_ri, Ct_ri, Bp, ls, atroots);
  k_Gab <<<dim3(1),    dim3(1024), 0, stream>>>(atroots, ab);
  k_conv<<<dim3(NROWS), dim3(512), 0, stream>>>(u, ab, Dp, (float*)d_out);
}